// Round 5
// baseline (139.689 us; speedup 1.0000x reference)
//
#include <hip/hip_runtime.h>

typedef float f32x4 __attribute__((ext_vector_type(4)));

// Problem constants (from reference setup_inputs)
constexpr int B  = 4;
constexpr int M  = 1088;
constexpr int HH = 32;
constexpr int D  = 128;
constexpr int F  = 128;
constexpr int C  = 512;

constexpr int SZ_YNUM = B * C * HH * D;   // 8388608
constexpr int SZ_YDEN = B * C * HH;       // 65536
constexpr int SZ_KVM  = B * M * HH * D;   // 17825792 (same for K, V, FK since D==F)
constexpr int SZ_H    = B * HH * F * D;   // 2097152

constexpr int OFF_YNUM = 0;
constexpr int OFF_YDEN = OFF_YNUM + SZ_YNUM;
constexpr int OFF_K    = OFF_YDEN + SZ_YDEN;
constexpr int OFF_V    = OFF_K + SZ_KVM;
constexpr int OFF_FK   = OFF_V + SZ_KVM;
constexpr int OFF_H    = OFF_FK + SZ_KVM;
constexpr int OFF_S    = OFF_H + SZ_H;

constexpr int INNER4      = HH * D / 4;    // 1024 f32x4 per (b,m) row
constexpr int ROWS_PER_CB = 4;             // rows copied per block (64 KB)
constexpr int COPY_BLOCKS = B * M / ROWS_PER_CB;  // 1088 (exact)
constexpr int HS_BLOCKS   = B * HH * 2;    // 256
constexpr int Y_BLOCKS    = B * HH * 8;    // 1024

__device__ __forceinline__ void ring_params(const int* wp_p, const int* valid_p,
                                            int& wp, int& num_excess, int& pos) {
    wp = *wp_p;
    int valid = *valid_p;
    if (valid + C <= M) {
        num_excess = 0;
        pos = (wp + valid) % M;
    } else {
        num_excess = valid + C - M;
        pos = (wp + num_excess) % M;
    }
}

// ---------------------------------------------------------------------------
// One copy block = ROWS_PER_CB (b,m)-rows (64 KB) of one (B,M,HH,128) tensor.
// Non-temporal on both sides: this data has zero reuse -> keep L2 clean.
// ---------------------------------------------------------------------------
__device__ __forceinline__ void ring_copy_block(int cb, int tid,
                                                const f32x4* __restrict__ src,
                                                const f32x4* __restrict__ chk,
                                                f32x4* __restrict__ dst,
                                                int pos) {
    int bm0 = cb * ROWS_PER_CB;
#pragma unroll
    for (int r = 0; r < ROWS_PER_CB; ++r) {
        int bm = bm0 + r;
        int m = bm % M;
        int b = bm / M;
        int off = m - pos;
        if (off < 0) off += M;
        const f32x4* s = (off < C) ? &chk[(b * C + off) * INNER4]
                                   : &src[bm * INNER4];
        f32x4* d = &dst[bm * INNER4];
        f32x4 t0 = __builtin_nontemporal_load(s + tid);
        f32x4 t1 = __builtin_nontemporal_load(s + 256 + tid);
        f32x4 t2 = __builtin_nontemporal_load(s + 512 + tid);
        f32x4 t3 = __builtin_nontemporal_load(s + 768 + tid);
        __builtin_nontemporal_store(t0, d + tid);
        __builtin_nontemporal_store(t1, d + 256 + tid);
        __builtin_nontemporal_store(t2, d + 512 + tid);
        __builtin_nontemporal_store(t3, d + 768 + tid);
    }
}

// ---------------------------------------------------------------------------
// update_hs body: block bx in [0,256). 64(f) x 128(d) tile of H[b,h].
// ESTEP=32, register double-buffered staging, b128 fk reads.
// ---------------------------------------------------------------------------
constexpr int ESTEP = 32;

__device__ void update_hs_body(int bx,
                               const float* __restrict__ FKi,
                               const float* __restrict__ Vi,
                               const float* __restrict__ Hi,
                               const float* __restrict__ Si,
                               float* __restrict__ Ho,
                               float* __restrict__ So,
                               int wp, int num_excess) {
    const int tid = threadIdx.x;
    const int fhalf = bx & 1;
    const int bh = bx >> 1;
    const int h = bh & (HH - 1);
    const int b = bh >> 5;
    const int fbase = fhalf * 64;

    __shared__ float  fk_s[ESTEP][64];   // 8 KB   (row stride 256 B, 16B-aligned)
    __shared__ f32x4  v_s[ESTEP][32];    // 16 KB
    __shared__ float  sred[4][64];       // 1 KB

    const int tf = tid >> 5;   // 0..7  (8 f-rows each)
    const int td = tid & 31;   // 0..31 (d quads)
    const int cq = tid & 63;   // fk column / s column
    const int qq = tid >> 6;   // quarter

    f32x4 acc[8];
#pragma unroll
    for (int i = 0; i < 8; ++i) acc[i] = (f32x4)0.f;
    float s_part = 0.f;

    float fk_r[8];
    f32x4 v_r[4];

    auto load_tile = [&](int e0) {
#pragma unroll
        for (int j = 0; j < 8; ++j) {
            int e = e0 + qq + 4 * j;
            int me = wp + e;
            if (me >= M) me -= M;
            if (me >= M) me -= M;
            float v = 0.f;
            if (e < num_excess) v = FKi[((b * M + me) * HH + h) * F + fbase + cq];
            fk_r[j] = v;
        }
#pragma unroll
        for (int j = 0; j < 4; ++j) {
            int e = e0 + tf + 8 * j;
            int me = wp + e;
            if (me >= M) me -= M;
            if (me >= M) me -= M;
            f32x4 v = (f32x4)0.f;
            if (e < num_excess) v = *(const f32x4*)&Vi[((b * M + me) * HH + h) * D + td * 4];
            v_r[j] = v;
        }
    };
    auto store_tile = [&]() {
#pragma unroll
        for (int j = 0; j < 8; ++j) fk_s[qq + 4 * j][cq] = fk_r[j];
#pragma unroll
        for (int j = 0; j < 4; ++j) v_s[tf + 8 * j][td] = v_r[j];
    };

    if (num_excess > 0) {
        load_tile(0);
        store_tile();
        for (int e0 = 0; e0 < num_excess; e0 += ESTEP) {
            bool more = (e0 + ESTEP < num_excess);
            if (more) load_tile(e0 + ESTEP);   // loads in flight during compute
            __syncthreads();                   // staged tile visible
#pragma unroll
            for (int ee = 0; ee < ESTEP; ++ee) {
                f32x4 fa = *(const f32x4*)&fk_s[ee][tf * 8];
                f32x4 fb = *(const f32x4*)&fk_s[ee][tf * 8 + 4];
                f32x4 vv = v_s[ee][td];
                acc[0] += fa.x * vv; acc[1] += fa.y * vv;
                acc[2] += fa.z * vv; acc[3] += fa.w * vv;
                acc[4] += fb.x * vv; acc[5] += fb.y * vv;
                acc[6] += fb.z * vv; acc[7] += fb.w * vv;
            }
#pragma unroll
            for (int j = 0; j < 8; ++j) s_part += fk_s[qq * 8 + j][cq];
            __syncthreads();                   // all reads done
            if (more) store_tile();            // waits vmcnt, writes next tile
        }
    }

    // S_new
    sred[qq][cq] = s_part;
    __syncthreads();
    if (tid < 64) {
        int f = fbase + tid;
        int si = (b * HH + h) * F + f;
        So[si] = Si[si] + sred[0][tid] + sred[1][tid] + sred[2][tid] + sred[3][tid];
    }

    // H_new = H_old + acc   (H_old streamed NT: read exactly once)
#pragma unroll
    for (int i = 0; i < 8; ++i) {
        int f = fbase + tf * 8 + i;
        int base = ((b * HH + h) * F + f) * D + td * 4;
        f32x4 hold = __builtin_nontemporal_load((const f32x4*)&Hi[base]);
        *(f32x4*)&Ho[base] = hold + acc[i];
    }
}

// ---------------------------------------------------------------------------
// compute_y_den body: block bx in [0,1024). 64(c) x 128(d) tile, f-step 32.
// ---------------------------------------------------------------------------
__device__ void compute_y_den_body(int bx,
                                   const float* __restrict__ fq,
                                   const float* __restrict__ Hn,
                                   const float* __restrict__ Sn,
                                   float* __restrict__ ynum,
                                   float* __restrict__ yden) {
    const int tid = threadIdx.x;
    int t = bx;
    const int ct = t & 7; t >>= 3;
    const int h = t & (HH - 1);
    const int b = t >> 5;
    const int c0 = ct * 64;

    __shared__ float  fq_s[32][65];   // [ee][c], padded
    __shared__ f32x4  h_s[32][32];    // [ee][d4]
    __shared__ float  S_s[128];
    __shared__ float  den_s[64][4];

    const int tc = tid >> 5;  // 0..7 (8 c-rows each)
    const int td = tid & 31;  // 0..31 (d quads)
    const int cq = tid & 63;
    const int qq = tid >> 6;

    if (tid < 128) S_s[tid] = Sn[(b * HH + h) * F + tid];

    f32x4 acc[8];
#pragma unroll
    for (int i = 0; i < 8; ++i) acc[i] = (f32x4)0.f;
    float den_part = 0.f;

    for (int f0 = 0; f0 < F; f0 += 32) {
        // fq tile: 64 c x 32 f (transposed); fq has no reuse -> NT loads
#pragma unroll
        for (int r = 0; r < 8; ++r) {
            int idx = tid + r * 256;
            int cc = idx >> 5, ee = idx & 31;
            fq_s[ee][cc] = __builtin_nontemporal_load(
                &fq[((b * C + c0 + cc) * HH + h) * F + f0 + ee]);
        }
        // H tile: 32 f x 128 d (reused by 8 ct-blocks -> cached loads)
#pragma unroll
        for (int r = 0; r < 4; ++r) {
            int idx = tid + r * 256;
            int row = idx >> 5, col = idx & 31;
            h_s[row][col] = *(const f32x4*)&Hn[((b * HH + h) * F + f0 + row) * D + col * 4];
        }
        __syncthreads();
#pragma unroll
        for (int ee = 0; ee < 32; ++ee) {
            f32x4 hv = h_s[ee][td];
#pragma unroll
            for (int i = 0; i < 8; ++i) {
                float q = fq_s[ee][tc * 8 + i];
                acc[i] += q * hv;
            }
        }
#pragma unroll
        for (int j = 0; j < 8; ++j)
            den_part += fq_s[qq * 8 + j][cq] * S_s[f0 + qq * 8 + j];
        __syncthreads();
    }

    den_s[cq][qq] = den_part;
    __syncthreads();
    if (tid < 64)
        yden[(b * C + c0 + tid) * HH + h] =
            den_s[tid][0] + den_s[tid][1] + den_s[tid][2] + den_s[tid][3];

#pragma unroll
    for (int i = 0; i < 8; ++i) {
        int c = c0 + tc * 8 + i;
        int base = ((b * C + c) * HH + h) * D + td * 4;
        __builtin_nontemporal_store(acc[i], (f32x4*)&ynum[base]);
    }
}

// ---------------------------------------------------------------------------
// Kernel 1: update_hs (blocks 0..255) + ALL three ring copies.
// V/FK copies first (share slice reads with hs in L3), K copy last.
// ---------------------------------------------------------------------------
__global__ __launch_bounds__(256) void fused_hs_copy(
        const float* __restrict__ FKi, const float* __restrict__ Vi,
        const float* __restrict__ Hi,  const float* __restrict__ Si,
        float* __restrict__ Ho,        float* __restrict__ So,
        const f32x4* __restrict__ V4,  const f32x4* __restrict__ vc,  f32x4* __restrict__ oV,
        const f32x4* __restrict__ FK4, const f32x4* __restrict__ fkc, f32x4* __restrict__ oFK,
        const f32x4* __restrict__ K4,  const f32x4* __restrict__ kc,  f32x4* __restrict__ oK,
        const int* __restrict__ wp_p,  const int* __restrict__ valid_p) {
    int wp, num_excess, pos;
    ring_params(wp_p, valid_p, wp, num_excess, pos);

    int bx = blockIdx.x;
    if (bx < HS_BLOCKS) {
        update_hs_body(bx, FKi, Vi, Hi, Si, Ho, So, wp, num_excess);
        return;
    }
    bx -= HS_BLOCKS;
    if (bx < COPY_BLOCKS) {
        ring_copy_block(bx, threadIdx.x, V4, vc, oV, pos);
        return;
    }
    bx -= COPY_BLOCKS;
    if (bx < COPY_BLOCKS) {
        ring_copy_block(bx, threadIdx.x, FK4, fkc, oFK, pos);
        return;
    }
    bx -= COPY_BLOCKS;
    ring_copy_block(bx, threadIdx.x, K4, kc, oK, pos);
}

// ---------------------------------------------------------------------------
// Kernel 2: compute_y_den only (reads H_new/S_new produced by kernel 1).
// ---------------------------------------------------------------------------
__global__ __launch_bounds__(256) void fused_y(
        const float* __restrict__ fq, const float* __restrict__ Hn,
        const float* __restrict__ Sn,
        float* __restrict__ ynum,     float* __restrict__ yden) {
    compute_y_den_body(blockIdx.x, fq, Hn, Sn, ynum, yden);
}

// ---------------------------------------------------------------------------
extern "C" void kernel_launch(void* const* d_in, const int* in_sizes, int n_in,
                              void* d_out, int out_size, void* d_ws, size_t ws_size,
                              hipStream_t stream) {
    const float* K   = (const float*)d_in[0];
    const float* V   = (const float*)d_in[1];
    const float* FK  = (const float*)d_in[2];
    const float* H   = (const float*)d_in[3];
    const float* S   = (const float*)d_in[4];
    const float* k_c = (const float*)d_in[5];
    const float* v_c = (const float*)d_in[6];
    const float* fk_c= (const float*)d_in[7];
    const float* fq  = (const float*)d_in[8];
    const int* wp    = (const int*)d_in[9];
    const int* valid = (const int*)d_in[10];

    float* out = (float*)d_out;
    float* o_ynum = out + OFF_YNUM;
    float* o_yden = out + OFF_YDEN;
    float* o_K    = out + OFF_K;
    float* o_V    = out + OFF_V;
    float* o_FK   = out + OFF_FK;
    float* o_H    = out + OFF_H;
    float* o_S    = out + OFF_S;

    // Kernel 1: H/S update overlapped with all three ring copies.
    fused_hs_copy<<<HS_BLOCKS + 3 * COPY_BLOCKS, 256, 0, stream>>>(
        FK, V, H, S, o_H, o_S,
        (const f32x4*)V,  (const f32x4*)v_c,  (f32x4*)o_V,
        (const f32x4*)FK, (const f32x4*)fk_c, (f32x4*)o_FK,
        (const f32x4*)K,  (const f32x4*)k_c,  (f32x4*)o_K,
        wp, valid);

    // Kernel 2: y_num/y_den (reads H_new, S_new).
    fused_y<<<Y_BLOCKS, 256, 0, stream>>>(fq, o_H, o_S, o_ynum, o_yden);
}